// Round 3
// baseline (20269.571 us; speedup 1.0000x reference)
//
#include <hip/hip_runtime.h>
#include <hip/hip_bf16.h>

typedef __attribute__((ext_vector_type(8))) short short8;
typedef __attribute__((ext_vector_type(4))) float f32x4;
typedef __attribute__((ext_vector_type(16))) float f32x16;
typedef unsigned long long u64;

#define MFMA16(A, B, C) __builtin_amdgcn_mfma_f32_16x16x32_bf16((A), (B), (C), 0, 0, 0)
#define MFMA32(A, B, C) __builtin_amdgcn_mfma_f32_32x32x16_bf16((A), (B), (C), 0, 0, 0)

static constexpr int kS = 512;   // seq
static constexpr int kI = 256;   // in_dim
static constexpr int kH = 2048;  // hidden
static constexpr int kC = 1024;  // classes
static constexpr int kBt = 256;  // batch

// LDS map (dynamic, 155904 B):
//   [0,      131072): Whh^T slice [n=32][k=2048] bf16, stride 4096 B, XOR swizzled
//   [131072, 147456): Whx^T slice [n=32][k=256]  bf16, stride 512 B,  XOR swizzled
//   [147456, 155904): reduction zone [64 rows][33] fp32 (pad +1 -> 2-way banks)
static constexpr int WHX_OFF  = 131072;
static constexpr int ZONE_OFF = 147456;

__device__ __forceinline__ int swz(int n, int kbyte, int rowstride) {
  return n * rowstride + (kbyte ^ ((n & 7) << 4));
}

__device__ __forceinline__ unsigned short f2bf(float f) {  // RNE fp32->bf16
  unsigned u = __float_as_uint(f);
  u += 0x7fffu + ((u >> 16) & 1u);
  return (unsigned short)(u >> 16);
}

__device__ __forceinline__ float fast_tanh(float v) {
  float a = __builtin_fabsf(v);
  float e = __expf(-2.0f * a);
  float r = (1.0f - e) / (1.0f + e);
  return __builtin_copysignf(r, v);
}

// Agent-scope relaxed atomics -> global_load/store sc0 sc1 (LLC-coherent,
// no buffer_wbl2/buffer_inv). Validated in round 2.
__device__ __forceinline__ u64 ld_h8(const u64* p) {
  return __hip_atomic_load(p, __ATOMIC_RELAXED, __HIP_MEMORY_SCOPE_AGENT);
}
__device__ __forceinline__ void st_h8(u64* p, u64 v) {
  __hip_atomic_store(p, v, __ATOMIC_RELAXED, __HIP_MEMORY_SCOPE_AGENT);
}
__device__ __forceinline__ unsigned ld_flag(const unsigned* p) {
  return __hip_atomic_load(p, __ATOMIC_RELAXED, __HIP_MEMORY_SCOPE_AGENT);
}
__device__ __forceinline__ void st_flag(unsigned* p, unsigned v) {
  __hip_atomic_store(p, v, __ATOMIC_RELAXED, __HIP_MEMORY_SCOPE_AGENT);
}

__global__ __launch_bounds__(512, 2)
void rnn_fused(const float* __restrict__ x, const float* __restrict__ Whx,
               const float* __restrict__ Whh, const float* __restrict__ Wph,
               const float* __restrict__ Bh, const float* __restrict__ Bp,
               float* __restrict__ out,
               u64* __restrict__ h0buf, u64* __restrict__ h1buf,
               unsigned* __restrict__ flags) {
  extern __shared__ char smem[];
  float* zone = (float*)(smem + ZONE_OFF);
  const int tid = (int)threadIdx.x;
  const int lane = tid & 63;
  const int wv = tid >> 6;          // 0..7
  const int wg = (int)blockIdx.x;
  const int rg = wg >> 6;           // 0..3  : 64-batch-row group (barrier domain)
  const int cg = wg & 63;           // 0..63 : 32-hidden-col group
  const int r0 = rg * 64;
  const int n0 = cg * 32;

  // ---- stage weight slices into LDS (fp32 -> bf16, swizzled), once
  {
    const int c = tid & 31;
    const int kk = tid >> 5;  // 16 k-stripes
    for (int k = kk; k < kH; k += 16)
      *(unsigned short*)(smem + swz(c, k * 2, 4096)) = f2bf(Whh[(size_t)k * kH + n0 + c]);
    for (int k = kk; k < kI; k += 16)
      *(unsigned short*)(smem + WHX_OFF + swz(c, k * 2, 512)) = f2bf(Whx[(size_t)k * kH + n0 + c]);
  }
  for (int i = tid; i < 64 * 33; i += 512) zone[i] = 0.f;
  __syncthreads();

  // 32x32x16 fragment geometry. Swapped operands: A = W^T (M=32 n-cols),
  // B = h^T (N=32 batch rows), D[n][row].
  const int j32 = lane & 31;         // A-row (n-col) == B-col (batch row)
  const int kb8 = (lane >> 5) * 8;   // lane's k offset within a 16-k step
  const int hi  = lane >> 5;
  const int kg  = wv;                // this wave's K-group (8-way K split)

  const int rowA = r0 + j32;         // batch row, tile 0
  const int rowB = rowA + 32;        // batch row, tile 1

  unsigned* gflags = flags + (rg << 6);
  const float* pxA = x + (size_t)rowA * (kS * kI);
  const float* pxB = x + (size_t)rowB * (kS * kI);
  const int xk0 = kg * 32 + kb8;     // x K range: 32 per wave
  const int hk0 = kg * 256;          // h K range: 256 per wave

  // epilogue geometry (fixed per thread): 1 row x 4 cols each
  const int erow = tid >> 3;
  const int ec0 = (tid & 7) * 4;
  const f32x4 bh = *(const f32x4*)(Bh + n0 + ec0);
  float* ezp = &zone[erow * 33 + ec0];

  for (int t = 0; t < kS; ++t) {
    const u64* hc = (t & 1) ? h1buf : h0buf;
    u64* hn       = (t & 1) ? h0buf : h1buf;
    f32x16 acc0 = {0.f,0.f,0.f,0.f,0.f,0.f,0.f,0.f,0.f,0.f,0.f,0.f,0.f,0.f,0.f,0.f};
    f32x16 acc1 = {0.f,0.f,0.f,0.f,0.f,0.f,0.f,0.f,0.f,0.f,0.f,0.f,0.f,0.f,0.f,0.f};

    // ---- x_t @ Whx (no h dependence: overlaps flag propagation below)
#pragma unroll
    for (int kb = 0; kb < 2; ++kb) {
      const int kgl = xk0 + kb * 16;
      short8 a = *(const short8*)(smem + WHX_OFF + swz(j32, kgl * 2, 512));
      f32x4 xa = *(const f32x4*)(pxA + (size_t)t * kI + kgl);
      f32x4 xb = *(const f32x4*)(pxA + (size_t)t * kI + kgl + 4);
      f32x4 ya = *(const f32x4*)(pxB + (size_t)t * kI + kgl);
      f32x4 yb = *(const f32x4*)(pxB + (size_t)t * kI + kgl + 4);
      short8 b0, b1;
#pragma unroll
      for (int j = 0; j < 4; ++j) {
        b0[j] = (short)f2bf(xa[j]); b0[j + 4] = (short)f2bf(xb[j]);
        b1[j] = (short)f2bf(ya[j]); b1[j + 4] = (short)f2bf(yb[j]);
      }
      acc0 = MFMA32(a, b0, acc0);
      acc1 = MFMA32(a, b1, acc1);
    }

    // ---- wait for h_t (all waves spin; 64 lanes poll 64 flags)
    if (t > 0) {
      while (!__all((int)(ld_flag(&gflags[lane]) >= (unsigned)t)))
        __builtin_amdgcn_s_sleep(1);
      asm volatile("" ::: "memory");
    }

    // ---- h_t @ Whh over this wave's 256-wide K slice
    {
      const u64* phA = hc + (size_t)rowA * (kH / 4);
      const u64* phB = hc + (size_t)rowB * (kH / 4);
#pragma unroll 8
      for (int kb = 0; kb < 16; ++kb) {
        const int kgl = hk0 + kb * 16 + kb8;
        short8 a = *(const short8*)(smem + swz(j32, kgl * 2, 4096));
        union { u64 q[2]; short8 s; } uA, uB;
        uA.q[0] = ld_h8(phA + (kgl >> 2));
        uA.q[1] = ld_h8(phA + (kgl >> 2) + 1);
        uB.q[0] = ld_h8(phB + (kgl >> 2));
        uB.q[1] = ld_h8(phB + (kgl >> 2) + 1);
        acc0 = MFMA32(a, uA.s, acc0);
        acc1 = MFMA32(a, uB.s, acc1);
      }
    }

    // ---- cross-wave K reduction: ds_add_f32 into padded zone
    // D layout: col(batch row)=lane&31, n-col=(r&3)+8*(r>>2)+4*(lane>>5)
#pragma unroll
    for (int r = 0; r < 16; ++r) {
      const int i = (r & 3) + 8 * (r >> 2) + 4 * hi;
      atomicAdd(&zone[j32 * 33 + i], acc0[r]);
      atomicAdd(&zone[(j32 + 32) * 33 + i], acc1[r]);
    }
    __syncthreads();

    // ---- epilogue: read+zero zone, tanh, pack 4 bf16 -> one 8B LLC store
    {
      float v0 = ezp[0], v1 = ezp[1], v2 = ezp[2], v3 = ezp[3];
      ezp[0] = 0.f; ezp[1] = 0.f; ezp[2] = 0.f; ezp[3] = 0.f;
      u64 pk = (u64)f2bf(fast_tanh(v0 + bh[0]))
             | ((u64)f2bf(fast_tanh(v1 + bh[1])) << 16)
             | ((u64)f2bf(fast_tanh(v2 + bh[2])) << 32)
             | ((u64)f2bf(fast_tanh(v3 + bh[3])) << 48);
      st_h8(hn + (size_t)(r0 + erow) * (kH / 4) + ((n0 + ec0) >> 2), pk);
    }
    __syncthreads();  // drains vmcnt(0): h stores ack'd at LLC before flag
    if (tid == 0) st_flag(&gflags[cg], (unsigned)(t + 1));
  }

  // ---- wait for whole rowgroup at step 512, then final projection
  while (!__all((int)(ld_flag(&gflags[lane]) >= (unsigned)kS)))
    __builtin_amdgcn_s_sleep(1);
  asm volatile("" ::: "memory");
  __syncthreads();

  // stage Wph^T slice [c=16][k=2048] into LDS region 0
  {
    const int c = tid & 15;
    const int kk = tid >> 4;  // 32 k-stripes
    for (int k = kk; k < kH; k += 32)
      *(unsigned short*)(smem + swz(c, k * 2, 4096)) = f2bf(Wph[(size_t)k * kC + cg * 16 + c]);
  }
  __syncthreads();

  // out = h_final @ Wph + Bp ; h_final in h0buf (t=511 wrote it). Waves 0-3.
  if (wv < 4) {
    const int bcol = lane & 15;
    const int kseg = lane >> 4;
    const int prow = r0 + wv * 16 + bcol;
    f32x4 acc = {0.f, 0.f, 0.f, 0.f};
    const u64* ph = h0buf + (size_t)prow * (kH / 4) + kseg * 2;
#pragma unroll 8
    for (int kb = 0; kb < kH / 32; ++kb) {
      union { u64 q[2]; short8 s; } u;
      u.q[0] = ld_h8(ph + kb * 8);
      u.q[1] = ld_h8(ph + kb * 8 + 1);
      short8 b = *(const short8*)(smem + swz(bcol, (kb * 32 + kseg * 8) * 2, 4096));
      acc = MFMA16(u.s, b, acc);  // A = h rows, B = Wph cols
    }
    const float bp = Bp[cg * 16 + bcol];
    const int orow = r0 + wv * 16 + kseg * 4;
#pragma unroll
    for (int j = 0; j < 4; ++j)
      out[(size_t)(orow + j) * kC + cg * 16 + bcol] = acc[j] + bp;
  }
}

extern "C" void kernel_launch(void* const* d_in, const int* in_sizes, int n_in,
                              void* d_out, int out_size, void* d_ws, size_t ws_size,
                              hipStream_t stream) {
  const float* x   = (const float*)d_in[0];
  const float* Whx = (const float*)d_in[1];
  const float* Whh = (const float*)d_in[2];
  const float* Wph = (const float*)d_in[3];
  const float* Bh  = (const float*)d_in[4];
  const float* Bp  = (const float*)d_in[5];
  float* out = (float*)d_out;

  char* ws = (char*)d_ws;
  u64* h0         = (u64*)(ws);                   // 1 MB: h ping
  u64* h1         = (u64*)(ws + (1 << 20));       // 1 MB: h pong
  unsigned* flags = (unsigned*)(ws + (2 << 20));  // 4 groups x 64 step flags

  hipMemsetAsync(h0, 0, (size_t)kBt * kH * sizeof(unsigned short), stream);  // h_0 = 0
  hipMemsetAsync(flags, 0, 4096, stream);                                    // reset barrier

  dim3 grid(256), block(512);
  size_t lds = 155904;  // 128K Whh + 16K Whx + 8.25K zone
  hipLaunchKernelGGL(rnn_fused, grid, block, lds, stream,
                     x, Whx, Whh, Wph, Bh, Bp, out, h0, h1, flags);
}

// Round 4
// 8829.243 us; speedup vs baseline: 2.2957x; 2.2957x over previous
//
#include <hip/hip_runtime.h>
#include <hip/hip_bf16.h>

typedef __attribute__((ext_vector_type(8))) short short8;
typedef __attribute__((ext_vector_type(4))) float f32x4;
typedef unsigned long long u64;

#define MFMA16(A, B, C) __builtin_amdgcn_mfma_f32_16x16x32_bf16((A), (B), (C), 0, 0, 0)

static constexpr int kS = 512;   // seq
static constexpr int kI = 256;   // in_dim
static constexpr int kH = 2048;  // hidden
static constexpr int kC = 1024;  // classes
static constexpr int kBt = 256;  // batch

// LDS map (dynamic, 155648 B):
//   [0,      131072): Whh^T slice [n=32][k=2048] bf16, stride 4096 B, XOR swizzled
//   [131072, 147456): Whx^T slice [n=32][k=256]  bf16, stride 512 B,  XOR swizzled
//   [147456, 155648): K-reduction zone [64 rows][8 colgroups x f32x4], cg XOR swizzle
static constexpr int WHX_OFF  = 131072;
static constexpr int ZONE_OFF = 147456;

__device__ __forceinline__ int swz(int n, int kbyte, int rowstride) {
  return n * rowstride + (kbyte ^ ((n & 7) << 4));
}

// zone cell (row 0..63, colgroup 0..7) -> swizzled f32x4 slot (no pad, 2-8 way max)
__device__ __forceinline__ float* zaddr(char* smem, int row, int cg) {
  return (float*)(smem + ZONE_OFF + ((row * 32 + ((cg ^ (row & 7)) << 2)) << 2));
}

__device__ __forceinline__ unsigned short f2bf(float f) {  // RNE fp32->bf16
  unsigned u = __float_as_uint(f);
  u += 0x7fffu + ((u >> 16) & 1u);
  return (unsigned short)(u >> 16);
}

__device__ __forceinline__ float fast_tanh(float v) {
  float a = __builtin_fabsf(v);
  float e = __expf(-2.0f * a);
  float r = (1.0f - e) / (1.0f + e);
  return __builtin_copysignf(r, v);
}

// Agent-scope relaxed atomics -> global_load/store sc0 sc1 (LLC-coherent, no
// buffer_wbl2/buffer_inv). Validated rounds 2-3.
__device__ __forceinline__ u64 ld_h8(const u64* p) {
  return __hip_atomic_load(p, __ATOMIC_RELAXED, __HIP_MEMORY_SCOPE_AGENT);
}
__device__ __forceinline__ void st_h8(u64* p, u64 v) {
  __hip_atomic_store(p, v, __ATOMIC_RELAXED, __HIP_MEMORY_SCOPE_AGENT);
}
__device__ __forceinline__ unsigned ld_flag(const unsigned* p) {
  return __hip_atomic_load(p, __ATOMIC_RELAXED, __HIP_MEMORY_SCOPE_AGENT);
}
__device__ __forceinline__ void st_flag(unsigned* p, unsigned v) {
  __hip_atomic_store(p, v, __ATOMIC_RELAXED, __HIP_MEMORY_SCOPE_AGENT);
}

__global__ __launch_bounds__(512, 2)
void rnn_fused(const float* __restrict__ x, const float* __restrict__ Whx,
               const float* __restrict__ Whh, const float* __restrict__ Wph,
               const float* __restrict__ Bh, const float* __restrict__ Bp,
               float* __restrict__ out,
               u64* __restrict__ h0buf, u64* __restrict__ h1buf,
               unsigned* __restrict__ flags) {
  extern __shared__ char smem[];
  const int tid = (int)threadIdx.x;
  const int lane = tid & 63;
  const int wv = tid >> 6;          // 0..7
  const int rb = wv & 3;            // row-block (16 rows)
  const int kh = wv >> 2;           // K-half (0 or 1)
  const int wg = (int)blockIdx.x;
  const int rg = wg >> 6;           // 0..3  : 64-batch-row group (barrier domain)
  const int cg = wg & 63;           // 0..63 : 32-hidden-col group
  const int r0 = rg * 64;
  const int n0 = cg * 32;

  // ---- stage weight slices into LDS (fp32 -> bf16, swizzled), once
  {
    const int c = tid & 31;
    const int kk = tid >> 5;  // 16 k-stripes
    for (int k = kk; k < kH; k += 16)
      *(unsigned short*)(smem + swz(c, k * 2, 4096)) = f2bf(Whh[(size_t)k * kH + n0 + c]);
    for (int k = kk; k < kI; k += 16)
      *(unsigned short*)(smem + WHX_OFF + swz(c, k * 2, 512)) = f2bf(Whx[(size_t)k * kH + n0 + c]);
  }
  __syncthreads();

  // 16x16x32 fragment geometry. Swapped operands: A = W^T (16 n-cols/tile),
  // B = h^T (16 batch rows). D[n][brow]: n = (lane>>4)*4+j, brow = lane&15.
  const int bcol = lane & 15;          // batch row within 16-row block; also A-row
  const int kseg = lane >> 4;          // k segment (0..3) * 8
  const int row_l = rb * 16 + bcol;    // local row 0..63
  const int grow  = r0 + row_l;        // global batch row

  unsigned* gflags = flags + (rg << 6);
  const float* px_row = x + (size_t)grow * (kS * kI);
  const int xk0 = kh * 128;            // this wave's x-K half
  const int hk0 = kh * 1024;           // this wave's h-K half

  const f32x4 bh0 = *(const f32x4*)(Bh + n0 + kseg * 4);
  const f32x4 bh1 = *(const f32x4*)(Bh + n0 + 16 + kseg * 4);

  for (int t = 0; t < kS; ++t) {
    const u64* hc = (t & 1) ? h1buf : h0buf;
    u64* hn       = (t & 1) ? h0buf : h1buf;
    f32x4 acc0 = {0.f, 0.f, 0.f, 0.f};
    f32x4 acc1 = {0.f, 0.f, 0.f, 0.f};

    // ---- x_t @ Whx over this wave's 128-wide K slice (no h dep: overlaps spin)
    {
      const float* px = px_row + (size_t)t * kI;
#pragma unroll
      for (int kb = 0; kb < 4; ++kb) {
        const int k = xk0 + kb * 32 + kseg * 8;
        f32x4 xa = *(const f32x4*)(px + k);
        f32x4 xb = *(const f32x4*)(px + k + 4);
        short8 b;
#pragma unroll
        for (int j = 0; j < 4; ++j) {
          b[j] = (short)f2bf(xa[j]);
          b[j + 4] = (short)f2bf(xb[j]);
        }
        short8 a0 = *(const short8*)(smem + WHX_OFF + swz(bcol, k * 2, 512));
        short8 a1 = *(const short8*)(smem + WHX_OFF + swz(16 + bcol, k * 2, 512));
        acc0 = MFMA16(a0, b, acc0);
        acc1 = MFMA16(a1, b, acc1);
      }
    }

    // ---- wait for h_t (every wave spins; 64 lanes poll 64 flags)
    if (t > 0) {
      while (!__all((int)(ld_flag(&gflags[lane]) >= (unsigned)t)))
        __builtin_amdgcn_s_sleep(1);
      asm volatile("" ::: "memory");
    }

    // ---- h_t @ Whh over this wave's 1024-wide K slice
    {
      const u64* ph = hc + (size_t)grow * (kH / 4);
#pragma unroll 8
      for (int kb = 0; kb < 32; ++kb) {
        const int k = hk0 + kb * 32 + kseg * 8;
        union { u64 q[2]; short8 s; } u;
        u.q[0] = ld_h8(ph + (k >> 2));
        u.q[1] = ld_h8(ph + (k >> 2) + 1);
        short8 a0 = *(const short8*)(smem + swz(bcol, k * 2, 4096));
        short8 a1 = *(const short8*)(smem + swz(16 + bcol, k * 2, 4096));
        acc0 = MFMA16(a0, u.s, acc0);
        acc1 = MFMA16(a1, u.s, acc1);
      }
    }

    // ---- K-half handoff: half 1 writes zone (non-atomic, each cell 1 owner)
    if (kh == 1) {
      *(f32x4*)zaddr(smem, row_l, kseg) = acc0;      // cg 0..3
      *(f32x4*)zaddr(smem, row_l, 4 + kseg) = acc1;  // cg 4..7
    }
    __syncthreads();

    // ---- half 0: combine, tanh, pack 4 bf16 -> one 8B LLC store per tile
    if (kh == 0) {
      f32x4 z0 = *(const f32x4*)zaddr(smem, row_l, kseg);
      f32x4 z1 = *(const f32x4*)zaddr(smem, row_l, 4 + kseg);
      u64 v0 = 0, v1 = 0;
#pragma unroll
      for (int j = 0; j < 4; ++j) {
        v0 |= (u64)f2bf(fast_tanh(acc0[j] + z0[j] + bh0[j])) << (16 * j);
        v1 |= (u64)f2bf(fast_tanh(acc1[j] + z1[j] + bh1[j])) << (16 * j);
      }
      u64* pr = hn + (size_t)grow * (kH / 4);
      st_h8(pr + ((n0 + kseg * 4) >> 2), v0);
      st_h8(pr + ((n0 + 16 + kseg * 4) >> 2), v1);
    }

    // ---- release: __syncthreads drains vmcnt(0) (h stores ack'd at LLC);
    // also fences zone reads of step t vs writes of step t+1
    __syncthreads();
    if (tid == 0) st_flag(&gflags[cg], (unsigned)(t + 1));
  }

  // ---- wait for whole rowgroup at step 512, then final projection
  while (!__all((int)(ld_flag(&gflags[lane]) >= (unsigned)kS)))
    __builtin_amdgcn_s_sleep(1);
  asm volatile("" ::: "memory");
  __syncthreads();

  // stage Wph^T slice [c=16][k=2048] into LDS region 0
  {
    const int c = tid & 15;
    const int kk = tid >> 4;  // 32 k-stripes
    for (int k = kk; k < kH; k += 32)
      *(unsigned short*)(smem + swz(c, k * 2, 4096)) = f2bf(Wph[(size_t)k * kC + cg * 16 + c]);
  }
  __syncthreads();

  // out = h_final @ Wph + Bp ; h_final in h0buf (t=511 wrote it). Waves 0-3.
  if (wv < 4) {
    const int prow = r0 + wv * 16 + bcol;
    f32x4 acc = {0.f, 0.f, 0.f, 0.f};
    const u64* ph = h0buf + (size_t)prow * (kH / 4) + kseg * 2;
#pragma unroll 8
    for (int kb = 0; kb < kH / 32; ++kb) {
      union { u64 q[2]; short8 s; } u;
      u.q[0] = ld_h8(ph + kb * 8);
      u.q[1] = ld_h8(ph + kb * 8 + 1);
      short8 b = *(const short8*)(smem + swz(bcol, (kb * 32 + kseg * 8) * 2, 4096));
      acc = MFMA16(u.s, b, acc);  // A = h rows, B = Wph cols
    }
    const float bp = Bp[cg * 16 + bcol];
    const int orow = r0 + wv * 16 + kseg * 4;
#pragma unroll
    for (int j = 0; j < 4; ++j)
      out[(size_t)(orow + j) * kC + cg * 16 + bcol] = acc[j] + bp;
  }
}

extern "C" void kernel_launch(void* const* d_in, const int* in_sizes, int n_in,
                              void* d_out, int out_size, void* d_ws, size_t ws_size,
                              hipStream_t stream) {
  const float* x   = (const float*)d_in[0];
  const float* Whx = (const float*)d_in[1];
  const float* Whh = (const float*)d_in[2];
  const float* Wph = (const float*)d_in[3];
  const float* Bh  = (const float*)d_in[4];
  const float* Bp  = (const float*)d_in[5];
  float* out = (float*)d_out;

  char* ws = (char*)d_ws;
  u64* h0         = (u64*)(ws);                   // 1 MB: h ping
  u64* h1         = (u64*)(ws + (1 << 20));       // 1 MB: h pong
  unsigned* flags = (unsigned*)(ws + (2 << 20));  // 4 groups x 64 step flags

  hipMemsetAsync(h0, 0, (size_t)kBt * kH * sizeof(unsigned short), stream);  // h_0 = 0
  hipMemsetAsync(flags, 0, 4096, stream);                                    // reset barrier

  dim3 grid(256), block(512);
  size_t lds = 155648;  // 128K Whh + 16K Whx + 8K zone
  hipLaunchKernelGGL(rnn_fused, grid, block, lds, stream,
                     x, Whx, Whh, Wph, Bh, Bp, out, h0, h1, flags);
}

// Round 5
// 5989.345 us; speedup vs baseline: 3.3843x; 1.4742x over previous
//
#include <hip/hip_runtime.h>
#include <hip/hip_bf16.h>

typedef __attribute__((ext_vector_type(8))) short short8;
typedef __attribute__((ext_vector_type(4))) float f32x4;
typedef unsigned long long u64;

#define MFMA16(A, B, C) __builtin_amdgcn_mfma_f32_16x16x32_bf16((A), (B), (C), 0, 0, 0)

static constexpr int kS = 512;   // seq
static constexpr int kI = 256;   // in_dim
static constexpr int kH = 2048;  // hidden
static constexpr int kC = 1024;  // classes
static constexpr int kBt = 256;  // batch

// WG tile: 32 batch rows x 64 hidden cols. Grid 256 = 8 rowgroups x 32 colgroups.
// Whh/Whx live in VGPRs (per wave: 16 cols x K-half). LDS:
//   [0,      131072): h-stage [32 rows][2048 k] bf16, row stride 4096 B, XOR swizzle
//                     (epilogue reuse: Wph^T [32 cls-cols][2048 k], same layout)
//   [131072, 139264): K-half zone [32 rows][16 quads x f32x4], XOR swizzle
static constexpr int ZONE_OFF = 131072;

__device__ __forceinline__ int swz(int row, int kbyte) {
  return row * 4096 + (kbyte ^ ((row & 7) << 4));
}
__device__ __forceinline__ f32x4* zslot(char* smem, int row, int quad) {  // 16 quads
  return (f32x4*)(smem + ZONE_OFF + row * 256 + (((quad ^ row) & 15) << 4));
}
__device__ __forceinline__ f32x4* zslot2(char* smem, int row, int quad) {  // 8 quads (epilogue)
  return (f32x4*)(smem + ZONE_OFF + row * 128 + (((quad ^ row) & 7) << 4));
}

__device__ __forceinline__ unsigned short f2bf(float f) {  // RNE fp32->bf16
  unsigned u = __float_as_uint(f);
  u += 0x7fffu + ((u >> 16) & 1u);
  return (unsigned short)(u >> 16);
}

__device__ __forceinline__ float fast_tanh(float v) {
  float a = __builtin_fabsf(v);
  float e = __expf(-2.0f * a);
  float r = (1.0f - e) / (1.0f + e);
  return __builtin_copysignf(r, v);
}

// Agent-scope relaxed atomics -> global_load/store sc0 sc1 (LLC-coherent, no
// buffer_wbl2/buffer_inv). Validated rounds 2-4.
__device__ __forceinline__ u64 ld_h8(const u64* p) {
  return __hip_atomic_load(p, __ATOMIC_RELAXED, __HIP_MEMORY_SCOPE_AGENT);
}
__device__ __forceinline__ void st_h8(u64* p, u64 v) {
  __hip_atomic_store(p, v, __ATOMIC_RELAXED, __HIP_MEMORY_SCOPE_AGENT);
}
__device__ __forceinline__ unsigned ld_flag(const unsigned* p) {
  return __hip_atomic_load(p, __ATOMIC_RELAXED, __HIP_MEMORY_SCOPE_AGENT);
}
__device__ __forceinline__ void st_flag(unsigned* p, unsigned v) {
  __hip_atomic_store(p, v, __ATOMIC_RELAXED, __HIP_MEMORY_SCOPE_AGENT);
}

__global__ __launch_bounds__(512, 2)
void rnn_fused(const float* __restrict__ x, const float* __restrict__ Whx,
               const float* __restrict__ Whh, const float* __restrict__ Wph,
               const float* __restrict__ Bh, const float* __restrict__ Bp,
               float* __restrict__ out,
               u64* __restrict__ h0buf, u64* __restrict__ h1buf,
               unsigned* __restrict__ flags) {
  extern __shared__ char smem[];
  const int tid = (int)threadIdx.x;
  const int lane = tid & 63;
  const int wv = tid >> 6;       // 0..7
  const int ci = wv & 3;         // 16-col group within WG
  const int kh = wv >> 2;        // K-half (0/1)
  const int wg = (int)blockIdx.x;
  const int rg = wg >> 5;        // 0..7  : rowgroup (32 rows, barrier domain)
  const int cg = wg & 31;        // 0..31 : colgroup (64 hidden cols)
  const int r0 = rg * 32;
  const int n0 = cg * 64;

  const int brow = lane & 15;    // batch row within 16-row tile; also A-row (col idx)
  const int nq = lane >> 4;      // k-segment / D col-quad
  const int klo = nq * 8;
  const int wcol = n0 + ci * 16 + brow;   // this lane's hidden col (A operand)

  // ---- persistent A fragments in VGPRs (one-time gather, L1/L2-cached)
  short8 wa[32];  // Whh^T: 16 cols x 1024 k (this wave's K-half)
#pragma unroll
  for (int kt = 0; kt < 32; ++kt) {
    const float* wp = Whh + (size_t)(kh * 1024 + kt * 32 + klo) * kH + wcol;
#pragma unroll
    for (int jj = 0; jj < 8; ++jj) wa[kt][jj] = (short)f2bf(wp[(size_t)jj * kH]);
  }
  short8 wx[4];   // Whx^T: 16 cols x 128 k (K-half of 256)
#pragma unroll
  for (int kt = 0; kt < 4; ++kt) {
    const float* wp = Whx + (size_t)(kh * 128 + kt * 32 + klo) * kH + wcol;
#pragma unroll
    for (int jj = 0; jj < 8; ++jj) wx[kt][jj] = (short)f2bf(wp[(size_t)jj * kH]);
  }

  const f32x4 bh = *(const f32x4*)(Bh + n0 + ci * 16 + nq * 4);  // kh==0 epilogue bias

  // stage geometry: thread -> (row, 16B chunk column)
  const int srow = tid >> 4;     // 0..31
  const int sc16 = tid & 15;

  unsigned* gflags = flags + (rg << 5);  // 32 flags per rowgroup
  const float* pxA = x + (size_t)(r0 + brow) * (kS * kI);        // rt=0 row
  const float* pxB = x + (size_t)(r0 + 16 + brow) * (kS * kI);   // rt=1 row

  for (int t = 0; t < kS; ++t) {
    const u64* hc = (t & 1) ? h1buf : h0buf;
    u64* hn       = (t & 1) ? h0buf : h1buf;
    f32x4 acc0 = {0.f, 0.f, 0.f, 0.f};
    f32x4 acc1 = {0.f, 0.f, 0.f, 0.f};

    // ---- x_t @ Whx over this wave's K-half (no h dep: overlaps flag wait)
#pragma unroll
    for (int kt = 0; kt < 4; ++kt) {
      const int k = kh * 128 + kt * 32 + klo;
      f32x4 xa = *(const f32x4*)(pxA + (size_t)t * kI + k);
      f32x4 xb = *(const f32x4*)(pxA + (size_t)t * kI + k + 4);
      f32x4 ya = *(const f32x4*)(pxB + (size_t)t * kI + k);
      f32x4 yb = *(const f32x4*)(pxB + (size_t)t * kI + k + 4);
      short8 b0, b1;
#pragma unroll
      for (int jj = 0; jj < 4; ++jj) {
        b0[jj] = (short)f2bf(xa[jj]); b0[jj + 4] = (short)f2bf(xb[jj]);
        b1[jj] = (short)f2bf(ya[jj]); b1[jj + 4] = (short)f2bf(yb[jj]);
      }
      acc0 = MFMA16(wx[kt], b0, acc0);
      acc1 = MFMA16(wx[kt], b1, acc1);
    }

    // ---- wait for h_t: only wave 0 polls (lanes poll 32 flags), rest park at barrier
    if (t > 0 && wv == 0) {
      while (!__all((int)(ld_flag(&gflags[lane & 31]) >= (unsigned)t)))
        __builtin_amdgcn_s_sleep(2);
      asm volatile("" ::: "memory");
    }
    __syncthreads();

    // ---- cooperative stage: h[32 rows x 2048] LLC -> LDS (16B per thread per iter)
    {
      const u64* hsrc = hc + (size_t)(r0 + srow) * 512;
#pragma unroll 4
      for (int i = 0; i < 16; ++i) {
        const int chunk = sc16 + i * 16;
        union { u64 q[2]; f32x4 v; } u;
        u.q[0] = ld_h8(hsrc + chunk * 2);
        u.q[1] = ld_h8(hsrc + chunk * 2 + 1);
        *(f32x4*)(smem + swz(srow, chunk * 16)) = u.v;
      }
    }
    __syncthreads();

    // ---- h_t @ Whh: A from VGPR, B from swizzled LDS
#pragma unroll
    for (int kt = 0; kt < 32; ++kt) {
      const int kb = (kh * 1024 + kt * 32 + klo) * 2;
      short8 hb0 = *(const short8*)(smem + swz(brow, kb));
      short8 hb1 = *(const short8*)(smem + swz(brow + 16, kb));
      acc0 = MFMA16(wa[kt], hb0, acc0);
      acc1 = MFMA16(wa[kt], hb1, acc1);
    }

    // ---- K-half handoff (non-atomic zone; each slot has one owner)
    if (kh == 1) {
      *zslot(smem, brow, ci * 4 + nq) = acc0;
      *zslot(smem, brow + 16, ci * 4 + nq) = acc1;
    }
    __syncthreads();

    // ---- kh==0: combine halves, tanh, pack 4 bf16 -> 8B LLC store per row-tile
    if (kh == 0) {
      f32x4 s0 = *zslot(smem, brow, ci * 4 + nq);
      f32x4 s1 = *zslot(smem, brow + 16, ci * 4 + nq);
      u64 v0 = 0, v1 = 0;
#pragma unroll
      for (int jj = 0; jj < 4; ++jj) {
        v0 |= (u64)f2bf(fast_tanh(acc0[jj] + s0[jj] + bh[jj])) << (16 * jj);
        v1 |= (u64)f2bf(fast_tanh(acc1[jj] + s1[jj] + bh[jj])) << (16 * jj);
      }
      const int qoff = (n0 >> 2) + ci * 4 + nq;
      st_h8(hn + (size_t)(r0 + brow) * 512 + qoff, v0);
      st_h8(hn + (size_t)(r0 + 16 + brow) * 512 + qoff, v1);
    }

    // ---- release: __syncthreads drains each wave's vmcnt (stores ack'd at LLC)
    __syncthreads();
    if (tid == 0) st_flag(&gflags[cg], (unsigned)(t + 1));
  }

  // ================= epilogue: out = h_final @ Wph + Bp =================
  if (wv == 0) {
    while (!__all((int)(ld_flag(&gflags[lane & 31]) >= (unsigned)kS)))
      __builtin_amdgcn_s_sleep(2);
    asm volatile("" ::: "memory");
  }
  __syncthreads();

  // stage Wph^T slice [32 cls-cols][2048 k] into h-stage region
  {
    const int c = tid & 31;
    const int kk = tid >> 5;  // 16 k-stripes
    for (int k = kk; k < kH; k += 16)
      *(unsigned short*)(smem + swz(c, k * 2)) = f2bf(Wph[(size_t)k * kC + cg * 32 + c]);
  }
  __syncthreads();

  // waves 0..3 active: (ci2 = wv&1 -> 16 cls-cols, kh2 = wv>>1 -> K-half)
  const bool act = (wv < 4);
  const int ci2 = wv & 1;
  const int kh2 = (wv >> 1) & 1;
  f32x4 oacc0 = {0.f, 0.f, 0.f, 0.f};
  f32x4 oacc1 = {0.f, 0.f, 0.f, 0.f};
  if (act) {
    const u64* phA = h0buf + (size_t)(r0 + brow) * 512;       // h_final (t=511 -> h0)
    const u64* phB = h0buf + (size_t)(r0 + 16 + brow) * 512;
#pragma unroll 8
    for (int kt = 0; kt < 32; ++kt) {
      const int gk = kh2 * 1024 + kt * 32 + klo;
      short8 a = *(const short8*)(smem + swz(ci2 * 16 + brow, gk * 2));
      union { u64 q[2]; short8 s; } uA, uB;
      uA.q[0] = ld_h8(phA + (gk >> 2)); uA.q[1] = ld_h8(phA + (gk >> 2) + 1);
      uB.q[0] = ld_h8(phB + (gk >> 2)); uB.q[1] = ld_h8(phB + (gk >> 2) + 1);
      oacc0 = MFMA16(a, uA.s, oacc0);
      oacc1 = MFMA16(a, uB.s, oacc1);
    }
  }
  if (act && kh2 == 1) {
    *zslot2(smem, brow, ci2 * 4 + nq) = oacc0;
    *zslot2(smem, brow + 16, ci2 * 4 + nq) = oacc1;
  }
  __syncthreads();
  if (act && kh2 == 0) {
    f32x4 s0 = *zslot2(smem, brow, ci2 * 4 + nq);
    f32x4 s1 = *zslot2(smem, brow + 16, ci2 * 4 + nq);
    const int ocol = cg * 32 + ci2 * 16 + nq * 4;
    const f32x4 bp = *(const f32x4*)(Bp + ocol);
#pragma unroll
    for (int jj = 0; jj < 4; ++jj) {
      out[(size_t)(r0 + brow) * kC + ocol + jj] = oacc0[jj] + s0[jj] + bp[jj];
      out[(size_t)(r0 + 16 + brow) * kC + ocol + jj] = oacc1[jj] + s1[jj] + bp[jj];
    }
  }
}

extern "C" void kernel_launch(void* const* d_in, const int* in_sizes, int n_in,
                              void* d_out, int out_size, void* d_ws, size_t ws_size,
                              hipStream_t stream) {
  const float* x   = (const float*)d_in[0];
  const float* Whx = (const float*)d_in[1];
  const float* Whh = (const float*)d_in[2];
  const float* Wph = (const float*)d_in[3];
  const float* Bh  = (const float*)d_in[4];
  const float* Bp  = (const float*)d_in[5];
  float* out = (float*)d_out;

  char* ws = (char*)d_ws;
  u64* h0         = (u64*)(ws);                   // 1 MB: h ping
  u64* h1         = (u64*)(ws + (1 << 20));       // 1 MB: h pong
  unsigned* flags = (unsigned*)(ws + (2 << 20));  // 8 groups x 32 step flags

  hipMemsetAsync(h0, 0, (size_t)kBt * kH * sizeof(unsigned short), stream);  // h_0 = 0
  hipMemsetAsync(flags, 0, 4096, stream);                                    // reset barrier

  dim3 grid(256), block(512);
  size_t lds = 139264;  // 128K h-stage + 8K zone
  hipLaunchKernelGGL(rnn_fused, grid, block, lds, stream,
                     x, Whx, Whh, Wph, Bh, Bp, out, h0, h1, flags);
}

// Round 7
// 4541.586 us; speedup vs baseline: 4.4631x; 1.3188x over previous
//
#include <hip/hip_runtime.h>
#include <hip/hip_bf16.h>

typedef __attribute__((ext_vector_type(8))) short short8;
typedef __attribute__((ext_vector_type(4))) float f32x4;
typedef unsigned long long u64;

#define MFMA16(A, B, C) __builtin_amdgcn_mfma_f32_16x16x32_bf16((A), (B), (C), 0, 0, 0)

static constexpr int kS = 512;   // seq
static constexpr int kI = 256;   // in_dim
static constexpr int kH = 2048;  // hidden
static constexpr int kC = 1024;  // classes
static constexpr int kBt = 256;  // batch

// WG tile: 32 batch rows x 64 hidden cols. Grid 256 = 8 rowgroups x 32 colgroups.
// Whh/Whx live in VGPRs (per wave: 16 cols x K-half). LDS:
//   [0,      131072): h-stage [32 rows][2048 k] bf16, row stride 4096 B, XOR swizzle
//                     (epilogue reuse: Wph^T [32 cls-cols][2048 k], same layout)
//   [131072, 139264): K-half zone [32 rows][16 quads x f32x4], XOR swizzle
static constexpr int ZONE_OFF = 131072;

__device__ __forceinline__ int swz(int row, int kbyte) {
  return row * 4096 + (kbyte ^ ((row & 7) << 4));
}
__device__ __forceinline__ f32x4* zslot(char* smem, int row, int quad) {  // 16 quads
  return (f32x4*)(smem + ZONE_OFF + row * 256 + (((quad ^ row) & 15) << 4));
}
__device__ __forceinline__ f32x4* zslot2(char* smem, int row, int quad) {  // 8 quads (epilogue)
  return (f32x4*)(smem + ZONE_OFF + row * 128 + (((quad ^ row) & 7) << 4));
}

__device__ __forceinline__ unsigned short f2bf(float f) {  // RNE fp32->bf16
  unsigned u = __float_as_uint(f);
  u += 0x7fffu + ((u >> 16) & 1u);
  return (unsigned short)(u >> 16);
}

__device__ __forceinline__ float fast_tanh(float v) {
  float a = __builtin_fabsf(v);
  float e = __expf(-2.0f * a);
  float r = (1.0f - e) / (1.0f + e);
  return __builtin_copysignf(r, v);
}

// Agent-scope relaxed atomics -> global_load/store sc0 sc1 (LLC-coherent, no
// buffer_wbl2/buffer_inv). Validated rounds 2-5. ALL sync-critical ops use
// these intrinsics only (round-6 lesson: hand-rolled cache bits on the flag
// path can deadlock; on the data path they can only cost accuracy).
__device__ __forceinline__ u64 ld_h8(const u64* p) {
  return __hip_atomic_load(p, __ATOMIC_RELAXED, __HIP_MEMORY_SCOPE_AGENT);
}
__device__ __forceinline__ void st_h8(u64* p, u64 v) {
  __hip_atomic_store(p, v, __ATOMIC_RELAXED, __HIP_MEMORY_SCOPE_AGENT);
}
__device__ __forceinline__ unsigned ld_flag(const unsigned* p) {
  return __hip_atomic_load(p, __ATOMIC_RELAXED, __HIP_MEMORY_SCOPE_AGENT);
}
__device__ __forceinline__ void st_flag(unsigned* p, unsigned v) {
  __hip_atomic_store(p, v, __ATOMIC_RELAXED, __HIP_MEMORY_SCOPE_AGENT);
}

__global__ __launch_bounds__(512, 2)
void rnn_fused(const float* __restrict__ x, const float* __restrict__ Whx,
               const float* __restrict__ Whh, const float* __restrict__ Wph,
               const float* __restrict__ Bh, const float* __restrict__ Bp,
               float* __restrict__ out,
               u64* __restrict__ h0buf, u64* __restrict__ h1buf,
               unsigned* __restrict__ flags) {
  extern __shared__ char smem[];
  const int tid = (int)threadIdx.x;
  const int lane = tid & 63;
  const int wv = tid >> 6;       // 0..7
  const int ci = wv & 3;         // 16-col group within WG
  const int kh = wv >> 2;        // K-half (0/1)
  const int wg = (int)blockIdx.x;
  const int rg = wg >> 5;        // 0..7  : rowgroup (32 rows, barrier domain)
  const int cg = wg & 31;        // 0..31 : colgroup (64 hidden cols)
  const int r0 = rg * 32;
  const int n0 = cg * 64;

  const int brow = lane & 15;    // batch row within 16-row tile; also A-row
  const int nq = lane >> 4;      // k-segment / D col-quad
  const int klo = nq * 8;
  const int wcol = n0 + ci * 16 + brow;   // this lane's hidden col (A operand)

  // ---- persistent A fragments in VGPRs (one-time gather, cached path)
  short8 wa[32];  // Whh^T: 16 cols x 1024 k (this wave's K-half)
#pragma unroll
  for (int kt = 0; kt < 32; ++kt) {
    const float* wp = Whh + (size_t)(kh * 1024 + kt * 32 + klo) * kH + wcol;
#pragma unroll
    for (int jj = 0; jj < 8; ++jj) wa[kt][jj] = (short)f2bf(wp[(size_t)jj * kH]);
  }
  short8 wx[4];   // Whx^T: 16 cols x 128 k (K-half of 256)
#pragma unroll
  for (int kt = 0; kt < 4; ++kt) {
    const float* wp = Whx + (size_t)(kh * 128 + kt * 32 + klo) * kH + wcol;
#pragma unroll
    for (int jj = 0; jj < 8; ++jj) wx[kt][jj] = (short)f2bf(wp[(size_t)jj * kH]);
  }

  const f32x4 bh = *(const f32x4*)(Bh + n0 + ci * 16 + nq * 4);

  // stage geometry: thread -> (row, 16B chunk); chunk j of this thread is at
  // byte sc16*16 + j*256 (threads interleave -> coalesced global + clean LDS)
  const int srow = tid >> 4;     // 0..31
  const int sc16 = tid & 15;

  unsigned* gflags = flags + (rg << 5);  // 32 flags per rowgroup
  const float* pxA = x + (size_t)(r0 + brow) * (kS * kI);
  const float* pxB = x + (size_t)(r0 + 16 + brow) * (kS * kI);

  for (int t = 0; t < kS; ++t) {
    const u64* hc = (t & 1) ? h1buf : h0buf;
    u64* hn       = (t & 1) ? h0buf : h1buf;
    f32x4 acc0 = {0.f, 0.f, 0.f, 0.f};
    f32x4 acc1 = {0.f, 0.f, 0.f, 0.f};

    // ---- x_t @ Whx over this wave's K-half (no h dep: overlaps flag wait)
#pragma unroll
    for (int kt = 0; kt < 4; ++kt) {
      const int k = kh * 128 + kt * 32 + klo;
      f32x4 xa = *(const f32x4*)(pxA + (size_t)t * kI + k);
      f32x4 xb = *(const f32x4*)(pxA + (size_t)t * kI + k + 4);
      f32x4 ya = *(const f32x4*)(pxB + (size_t)t * kI + k);
      f32x4 yb = *(const f32x4*)(pxB + (size_t)t * kI + k + 4);
      short8 b0, b1;
#pragma unroll
      for (int jj = 0; jj < 4; ++jj) {
        b0[jj] = (short)f2bf(xa[jj]); b0[jj + 4] = (short)f2bf(xb[jj]);
        b1[jj] = (short)f2bf(ya[jj]); b1[jj + 4] = (short)f2bf(yb[jj]);
      }
      acc0 = MFMA16(wx[kt], b0, acc0);
      acc1 = MFMA16(wx[kt], b1, acc1);
    }

    // ---- wait for h_t: only wave 0 polls (intrinsic path), rest park at barrier
    if (t > 0 && wv == 0) {
      while (!__all((int)(ld_flag(&gflags[lane & 31]) >= (unsigned)t)))
        __builtin_amdgcn_s_sleep(2);
      asm volatile("" ::: "memory");
    }
    __syncthreads();

    // ---- cooperative stage: h[32 x 2048] LLC -> LDS.
    // 16B sc0sc1 loads (same coherence point as the validated agent
    // intrinsics), 2 batches of 8 in flight -> 2M instead of 4M requests/step.
    {
      const char* hp = (const char*)hc + (size_t)(r0 + srow) * 4096 + sc16 * 16;
      {
        f32x4 a0, a1, a2, a3, a4, a5, a6, a7;
        asm volatile(
            "global_load_dwordx4 %0, %8, off sc0 sc1\n\t"
            "global_load_dwordx4 %1, %8, off offset:256 sc0 sc1\n\t"
            "global_load_dwordx4 %2, %8, off offset:512 sc0 sc1\n\t"
            "global_load_dwordx4 %3, %8, off offset:768 sc0 sc1\n\t"
            "global_load_dwordx4 %4, %8, off offset:1024 sc0 sc1\n\t"
            "global_load_dwordx4 %5, %8, off offset:1280 sc0 sc1\n\t"
            "global_load_dwordx4 %6, %8, off offset:1536 sc0 sc1\n\t"
            "global_load_dwordx4 %7, %8, off offset:1792 sc0 sc1"
            : "=&v"(a0), "=&v"(a1), "=&v"(a2), "=&v"(a3),
              "=&v"(a4), "=&v"(a5), "=&v"(a6), "=&v"(a7)
            : "v"(hp) : "memory");
        asm volatile("s_waitcnt vmcnt(0)" ::: "memory");
        __builtin_amdgcn_sched_barrier(0);
        const int kb = sc16 * 16;
        *(f32x4*)(smem + swz(srow, kb))        = a0;
        *(f32x4*)(smem + swz(srow, kb + 256))  = a1;
        *(f32x4*)(smem + swz(srow, kb + 512))  = a2;
        *(f32x4*)(smem + swz(srow, kb + 768))  = a3;
        *(f32x4*)(smem + swz(srow, kb + 1024)) = a4;
        *(f32x4*)(smem + swz(srow, kb + 1280)) = a5;
        *(f32x4*)(smem + swz(srow, kb + 1536)) = a6;
        *(f32x4*)(smem + swz(srow, kb + 1792)) = a7;
      }
      {
        f32x4 a0, a1, a2, a3, a4, a5, a6, a7;
        asm volatile(
            "global_load_dwordx4 %0, %8, off offset:2048 sc0 sc1\n\t"
            "global_load_dwordx4 %1, %8, off offset:2304 sc0 sc1\n\t"
            "global_load_dwordx4 %2, %8, off offset:2560 sc0 sc1\n\t"
            "global_load_dwordx4 %3, %8, off offset:2816 sc0 sc1\n\t"
            "global_load_dwordx4 %4, %8, off offset:3072 sc0 sc1\n\t"
            "global_load_dwordx4 %5, %8, off offset:3328 sc0 sc1\n\t"
            "global_load_dwordx4 %6, %8, off offset:3584 sc0 sc1\n\t"
            "global_load_dwordx4 %7, %8, off offset:3840 sc0 sc1"
            : "=&v"(a0), "=&v"(a1), "=&v"(a2), "=&v"(a3),
              "=&v"(a4), "=&v"(a5), "=&v"(a6), "=&v"(a7)
            : "v"(hp) : "memory");
        asm volatile("s_waitcnt vmcnt(0)" ::: "memory");
        __builtin_amdgcn_sched_barrier(0);
        const int kb = sc16 * 16 + 2048;
        *(f32x4*)(smem + swz(srow, kb))        = a0;
        *(f32x4*)(smem + swz(srow, kb + 256))  = a1;
        *(f32x4*)(smem + swz(srow, kb + 512))  = a2;
        *(f32x4*)(smem + swz(srow, kb + 768))  = a3;
        *(f32x4*)(smem + swz(srow, kb + 1024)) = a4;
        *(f32x4*)(smem + swz(srow, kb + 1280)) = a5;
        *(f32x4*)(smem + swz(srow, kb + 1536)) = a6;
        *(f32x4*)(smem + swz(srow, kb + 1792)) = a7;
      }
    }
    __syncthreads();

    // ---- h_t @ Whh: A from VGPR, B from swizzled LDS
#pragma unroll
    for (int kt = 0; kt < 32; ++kt) {
      const int kb = (kh * 1024 + kt * 32 + klo) * 2;
      short8 hb0 = *(const short8*)(smem + swz(brow, kb));
      short8 hb1 = *(const short8*)(smem + swz(brow + 16, kb));
      acc0 = MFMA16(wa[kt], hb0, acc0);
      acc1 = MFMA16(wa[kt], hb1, acc1);
    }

    // ---- K-half handoff (non-atomic zone; one owner per slot)
    if (kh == 1) {
      *zslot(smem, brow, ci * 4 + nq) = acc0;
      *zslot(smem, brow + 16, ci * 4 + nq) = acc1;
    }
    __syncthreads();

    // ---- kh==0: combine halves, tanh, pack 4 bf16 -> 8B LLC store per row-tile
    if (kh == 0) {
      f32x4 s0 = *zslot(smem, brow, ci * 4 + nq);
      f32x4 s1 = *zslot(smem, brow + 16, ci * 4 + nq);
      u64 v0 = 0, v1 = 0;
#pragma unroll
      for (int jj = 0; jj < 4; ++jj) {
        v0 |= (u64)f2bf(fast_tanh(acc0[jj] + s0[jj] + bh[jj])) << (16 * jj);
        v1 |= (u64)f2bf(fast_tanh(acc1[jj] + s1[jj] + bh[jj])) << (16 * jj);
      }
      const int qoff = (n0 >> 2) + ci * 4 + nq;
      st_h8(hn + (size_t)(r0 + brow) * 512 + qoff, v0);
      st_h8(hn + (size_t)(r0 + 16 + brow) * 512 + qoff, v1);
    }

    // ---- release: __syncthreads drains each wave's vmcnt (stores ack'd at LLC)
    __syncthreads();
    if (tid == 0) st_flag(&gflags[cg], (unsigned)(t + 1));
  }

  // ================= epilogue: out = h_final @ Wph + Bp =================
  if (wv == 0) {
    while (!__all((int)(ld_flag(&gflags[lane & 31]) >= (unsigned)kS)))
      __builtin_amdgcn_s_sleep(2);
    asm volatile("" ::: "memory");
  }
  __syncthreads();

  // stage Wph^T slice [32 cls-cols][2048 k] into h-stage region
  {
    const int c = tid & 31;
    const int kk = tid >> 5;  // 16 k-stripes
    for (int k = kk; k < kH; k += 16)
      *(unsigned short*)(smem + swz(c, k * 2)) = f2bf(Wph[(size_t)k * kC + cg * 32 + c]);
  }
  __syncthreads();

  // waves 0..3 active: (ci2 = wv&1 -> 16 cls-cols, kh2 = wv>>1 -> K-half)
  const bool act = (wv < 4);
  const int ci2 = wv & 1;
  const int kh2 = (wv >> 1) & 1;
  f32x4 oacc0 = {0.f, 0.f, 0.f, 0.f};
  f32x4 oacc1 = {0.f, 0.f, 0.f, 0.f};
  if (act) {
    const u64* phA = h0buf + (size_t)(r0 + brow) * 512;       // h_final (t=511 -> h0)
    const u64* phB = h0buf + (size_t)(r0 + 16 + brow) * 512;
#pragma unroll 8
    for (int kt = 0; kt < 32; ++kt) {
      const int gk = kh2 * 1024 + kt * 32 + klo;
      short8 a = *(const short8*)(smem + swz(ci2 * 16 + brow, gk * 2));
      union { u64 q[2]; short8 s; } uA, uB;
      uA.q[0] = ld_h8(phA + (gk >> 2)); uA.q[1] = ld_h8(phA + (gk >> 2) + 1);
      uB.q[0] = ld_h8(phB + (gk >> 2)); uB.q[1] = ld_h8(phB + (gk >> 2) + 1);
      oacc0 = MFMA16(a, uA.s, oacc0);
      oacc1 = MFMA16(a, uB.s, oacc1);
    }
  }
  if (act && kh2 == 1) {
    *zslot2(smem, brow, ci2 * 4 + nq) = oacc0;
    *zslot2(smem, brow + 16, ci2 * 4 + nq) = oacc1;
  }
  __syncthreads();
  if (act && kh2 == 0) {
    f32x4 s0 = *zslot2(smem, brow, ci2 * 4 + nq);
    f32x4 s1 = *zslot2(smem, brow + 16, ci2 * 4 + nq);
    const int ocol = cg * 32 + ci2 * 16 + nq * 4;
    const f32x4 bp = *(const f32x4*)(Bp + ocol);
#pragma unroll
    for (int jj = 0; jj < 4; ++jj) {
      out[(size_t)(r0 + brow) * kC + ocol + jj] = oacc0[jj] + s0[jj] + bp[jj];
      out[(size_t)(r0 + 16 + brow) * kC + ocol + jj] = oacc1[jj] + s1[jj] + bp[jj];
    }
  }
}

extern "C" void kernel_launch(void* const* d_in, const int* in_sizes, int n_in,
                              void* d_out, int out_size, void* d_ws, size_t ws_size,
                              hipStream_t stream) {
  const float* x   = (const float*)d_in[0];
  const float* Whx = (const float*)d_in[1];
  const float* Whh = (const float*)d_in[2];
  const float* Wph = (const float*)d_in[3];
  const float* Bh  = (const float*)d_in[4];
  const float* Bp  = (const float*)d_in[5];
  float* out = (float*)d_out;

  char* ws = (char*)d_ws;
  u64* h0         = (u64*)(ws);                   // 1 MB: h ping
  u64* h1         = (u64*)(ws + (1 << 20));       // 1 MB: h pong
  unsigned* flags = (unsigned*)(ws + (2 << 20));  // 8 groups x 32 step flags

  hipMemsetAsync(h0, 0, (size_t)kBt * kH * sizeof(unsigned short), stream);  // h_0 = 0
  hipMemsetAsync(flags, 0, 4096, stream);                                    // reset barrier

  dim3 grid(256), block(512);
  size_t lds = 139264;  // 128K h-stage + 8K zone
  hipLaunchKernelGGL(rnn_fused, grid, block, lds, stream,
                     x, Whx, Whh, Wph, Bh, Bp, out, h0, h1, flags);
}